// Round 1
// baseline (303.295 us; speedup 1.0000x reference)
//
#include <hip/hip_runtime.h>
#include <stdint.h>

// HashGrid encode, instant-ngp/tcnn defaults, Smoothstep interpolation.
// 16 levels, F=2, T=2^19, base_res=16, per_level_scale=2.0, 2D input.
// Levels 0..5 dense (res=16<<l, res^2 <= T), levels 6..15 hashed.

#define HG_LEVELS 16
#define HG_T (1u << 19)
#define HG_PRIME1 2654435761u

__global__ __launch_bounds__(256) void hashgrid_encode_kernel(
    const float2* __restrict__ x,       // [N] points, each (x,y) in [-1,1]
    const float* __restrict__ table,    // [16][T][2]
    float* __restrict__ out,            // [N][32]
    int npts)
{
    int i = blockIdx.x * blockDim.x + threadIdx.x;
    if (i >= npts) return;

    float2 xi = x[i];
    // wrapper maps [-1,1] -> [0,1]
    float x0 = xi.x * 0.5f + 0.5f;
    float x1 = xi.y * 0.5f + 0.5f;

    float acc[2 * HG_LEVELS];

#pragma unroll
    for (int l = 0; l < HG_LEVELS; ++l) {
        const int res = 16 << l;                  // = ceil(scale)+1, exact
        const float scale = (float)res - 1.0f;    // 2^l*16 - 1, exactly representable
        const bool dense = (l <= 5);              // res*res <= T

        float p0 = x0 * scale + 0.5f;
        float p1 = x1 * scale + 0.5f;
        float g0 = floorf(p0);
        float g1 = floorf(p1);
        float fr0 = p0 - g0;
        float fr1 = p1 - g1;
        uint32_t c0 = (uint32_t)(int)g0;          // pg >= 0 always (pos >= 0.5)
        uint32_t c1 = (uint32_t)(int)g1;

        // smoothstep weights
        float w0 = fr0 * fr0 * (3.0f - 2.0f * fr0);
        float w1 = fr1 * fr1 * (3.0f - 2.0f * fr1);

        uint32_t i00, i10, i01, i11;
        if (dense) {
            const uint32_t mask = (uint32_t)res * (uint32_t)res - 1u;  // power of two
            uint32_t r0 = c0;
            uint32_t r1 = c0 + 1u;
            uint32_t b0 = c1 * (uint32_t)res;
            uint32_t b1 = (c1 + 1u) * (uint32_t)res;
            i00 = (r0 + b0) & mask;
            i10 = (r1 + b0) & mask;
            i01 = (r0 + b1) & mask;
            i11 = (r1 + b1) & mask;
        } else {
            uint32_t h0 = c1 * HG_PRIME1;
            uint32_t h1 = (c1 + 1u) * HG_PRIME1;
            i00 = (c0 ^ h0) & (HG_T - 1u);
            i10 = ((c0 + 1u) ^ h0) & (HG_T - 1u);
            i01 = (c0 ^ h1) & (HG_T - 1u);
            i11 = ((c0 + 1u) ^ h1) & (HG_T - 1u);
        }

        const float* tl = table + (size_t)l * (size_t)HG_T * 2u;
        float2 f00 = *(const float2*)(tl + (size_t)i00 * 2u);
        float2 f10 = *(const float2*)(tl + (size_t)i10 * 2u);
        float2 f01 = *(const float2*)(tl + (size_t)i01 * 2u);
        float2 f11 = *(const float2*)(tl + (size_t)i11 * 2u);

        float w00 = (1.0f - w0) * (1.0f - w1);
        float w10 = w0 * (1.0f - w1);
        float w01 = (1.0f - w0) * w1;
        float w11 = w0 * w1;

        acc[2 * l + 0] = w00 * f00.x + w10 * f10.x + w01 * f01.x + w11 * f11.x;
        acc[2 * l + 1] = w00 * f00.y + w10 * f10.y + w01 * f01.y + w11 * f11.y;
    }

    // out[i][0..31], write as 8x float4 (per-thread contiguous 128B)
    float4* o = (float4*)(out + (size_t)i * (2 * HG_LEVELS));
#pragma unroll
    for (int j = 0; j < 8; ++j) {
        o[j] = make_float4(acc[4 * j + 0], acc[4 * j + 1], acc[4 * j + 2], acc[4 * j + 3]);
    }
}

extern "C" void kernel_launch(void* const* d_in, const int* in_sizes, int n_in,
                              void* d_out, int out_size, void* d_ws, size_t ws_size,
                              hipStream_t stream) {
    const float2* x = (const float2*)d_in[0];
    const float* table = (const float*)d_in[1];
    float* out = (float*)d_out;

    int npts = in_sizes[0] / 2;  // 64*64*128 = 524288
    int block = 256;
    int grid = (npts + block - 1) / block;
    hashgrid_encode_kernel<<<grid, block, 0, stream>>>(x, table, out, npts);
}

// Round 3
// 266.579 us; speedup vs baseline: 1.1377x; 1.1377x over previous
//
#include <hip/hip_runtime.h>
#include <stdint.h>

// HashGrid encode, instant-ngp/tcnn defaults, Smoothstep interpolation.
// 16 levels, F=2, T=2^19, base_res=16, per_level_scale=2.0, 2D input.
// Levels 0..5 dense (res=16<<l, res^2 <= T), levels 6..15 hashed (4 MiB table each).
//
// Round 2 structure: 2 points per thread, level-major loop with per-level
// __syncthreads() on hashed levels so each XCD's 4 MiB L2 holds only the
// currently-active level's table (level phasing). 8 gathers in flight per
// wave per level for MLP.

#define HG_LEVELS 16
#define HG_T (1u << 19)
#define HG_PRIME1 2654435761u

__device__ __forceinline__ void level_setup(float x0, float x1, int l,
                                            uint32_t idx[4], float w[4])
{
    const int res = 16 << l;                   // = ceil(scale)+1, exact
    const float scale = (float)res - 1.0f;     // exactly representable
    float p0 = x0 * scale + 0.5f;
    float p1 = x1 * scale + 0.5f;
    float g0 = floorf(p0);
    float g1 = floorf(p1);
    float fr0 = p0 - g0;
    float fr1 = p1 - g1;
    uint32_t c0 = (uint32_t)(int)g0;           // pos >= 0.5 so pg >= 0
    uint32_t c1 = (uint32_t)(int)g1;
    float w0 = fr0 * fr0 * (3.0f - 2.0f * fr0);   // smoothstep
    float w1 = fr1 * fr1 * (3.0f - 2.0f * fr1);

    if (l <= 5) {
        const uint32_t mask = (uint32_t)res * (uint32_t)res - 1u;  // pow2
        uint32_t b0 = c1 * (uint32_t)res;
        uint32_t b1 = (c1 + 1u) * (uint32_t)res;
        idx[0] = (c0 + b0) & mask;
        idx[1] = (c0 + 1u + b0) & mask;
        idx[2] = (c0 + b1) & mask;
        idx[3] = (c0 + 1u + b1) & mask;
    } else {
        uint32_t h0 = c1 * HG_PRIME1;
        uint32_t h1 = (c1 + 1u) * HG_PRIME1;
        idx[0] = (c0 ^ h0) & (HG_T - 1u);
        idx[1] = ((c0 + 1u) ^ h0) & (HG_T - 1u);
        idx[2] = (c0 ^ h1) & (HG_T - 1u);
        idx[3] = ((c0 + 1u) ^ h1) & (HG_T - 1u);
    }
    w[0] = (1.0f - w0) * (1.0f - w1);
    w[1] = w0 * (1.0f - w1);
    w[2] = (1.0f - w0) * w1;
    w[3] = w0 * w1;
}

__global__ __launch_bounds__(256) void hashgrid_encode2_kernel(
    const float4* __restrict__ x,       // [npairs] = two points (x0,y0,x1,y1)
    const float* __restrict__ table,    // [16][T][2]
    float* __restrict__ out,            // [2*npairs][32]
    int npairs)
{
    int t = blockIdx.x * blockDim.x + threadIdx.x;
    // clamp instead of early-return: keeps __syncthreads() uniform
    if (t >= npairs) t = npairs - 1;

    float4 xp = x[t];
    float a0 = xp.x * 0.5f + 0.5f;      // point A in [0,1]
    float a1 = xp.y * 0.5f + 0.5f;
    float b0 = xp.z * 0.5f + 0.5f;      // point B
    float b1 = xp.w * 0.5f + 0.5f;

    float accA[2 * HG_LEVELS];
    float accB[2 * HG_LEVELS];

#pragma unroll
    for (int l = 0; l < HG_LEVELS; ++l) {
        uint32_t ia[4], ib[4];
        float wa[4], wb[4];
        level_setup(a0, a1, l, ia, wa);
        level_setup(b0, b1, l, ib, wb);

        const float2* tl = (const float2*)(table + (size_t)l * (size_t)HG_T * 2u);
        float2 fa[4], fb[4];
#pragma unroll
        for (int c = 0; c < 4; ++c) fa[c] = tl[ia[c]];
#pragma unroll
        for (int c = 0; c < 4; ++c) fb[c] = tl[ib[c]];

        float sAx = 0.f, sAy = 0.f, sBx = 0.f, sBy = 0.f;
#pragma unroll
        for (int c = 0; c < 4; ++c) {
            sAx += wa[c] * fa[c].x;
            sAy += wa[c] * fa[c].y;
            sBx += wb[c] * fb[c].x;
            sBy += wb[c] * fb[c].y;
        }
        accA[2 * l + 0] = sAx;
        accA[2 * l + 1] = sAy;
        accB[2 * l + 0] = sBx;
        accB[2 * l + 1] = sBy;

        // level phasing: keep the block's waves on the same hashed level so
        // the active 4 MiB table stays resident in each XCD's L2
        if (l >= 5 && l < HG_LEVELS - 1) __syncthreads();
    }

    // two full 128B rows per thread; back-to-back float4 stores merge in L2
    float4* oA = (float4*)(out + (size_t)(2 * t + 0) * (2 * HG_LEVELS));
    float4* oB = (float4*)(out + (size_t)(2 * t + 1) * (2 * HG_LEVELS));
#pragma unroll
    for (int j = 0; j < 8; ++j)
        oA[j] = make_float4(accA[4 * j + 0], accA[4 * j + 1],
                            accA[4 * j + 2], accA[4 * j + 3]);
#pragma unroll
    for (int j = 0; j < 8; ++j)
        oB[j] = make_float4(accB[4 * j + 0], accB[4 * j + 1],
                            accB[4 * j + 2], accB[4 * j + 3]);
}

extern "C" void kernel_launch(void* const* d_in, const int* in_sizes, int n_in,
                              void* d_out, int out_size, void* d_ws, size_t ws_size,
                              hipStream_t stream) {
    const float4* x = (const float4*)d_in[0];
    const float* table = (const float*)d_in[1];
    float* out = (float*)d_out;

    int npts = in_sizes[0] / 2;          // 524288
    int npairs = npts / 2;               // 262144
    int block = 256;
    int grid = (npairs + block - 1) / block;   // 1024
    hashgrid_encode2_kernel<<<grid, block, 0, stream>>>(x, table, out, npairs);
}